// Round 10
// baseline (222.101 us; speedup 1.0000x reference)
//
#include <hip/hip_runtime.h>

#define HH 8
#define NN 32
#define TT 2048
#define DD 256

typedef float f4 __attribute__((ext_vector_type(4)));
typedef float f32x4 __attribute__((ext_vector_type(4)));
typedef _Float16 f16x8 __attribute__((ext_vector_type(8)));
typedef unsigned short u16;
typedef u16 u16x8 __attribute__((ext_vector_type(8)));

__device__ __forceinline__ u16 f2h(float x) {
  _Float16 h = (_Float16)x;
  return *(u16*)&h;
}

// Fast tanh: 1 - 2*rcp(exp(2|x|)+1), sign via copysign. 2 trans + ~6 full-rate.
__device__ __forceinline__ float ftanh(float x) {
  float ax = __builtin_fabsf(x);
  float e = __expf(ax + ax);
  float t = 1.f - __fdividef(2.f, e + 1.f);
  return __builtin_copysignf(t, x);
}

__device__ __forceinline__ void gl_lds16(const void* g, void* l) {
  __builtin_amdgcn_global_load_lds((const __attribute__((address_space(1))) unsigned*)g,
                                   (__attribute__((address_space(3))) unsigned*)l, 16, 0, 0);
}

// ===========================================================================
// Packed operand layout (verified R2-R6), 128-row regions:
// per 8KB region = [128 rows][32 k] f16:
//   line = row>>1 (128B lines of 8 x 16B slots), line in [0,64);
//   slot pos = (ksl | ((row&1)<<2)) ^ (line&7)   (XOR bank swizzle);
//   within slot, u16 j holds k = ks*32 + ksl*4 + {0,1,2,3,16,17,18,19}[j]
//   (k-pattern of mfma_f32_16x16x32 operand fragments, verified R0/R1).
// Regions are operand-role agnostic ([row][k]); row = the non-K dim.
// ===========================================================================

// Merged pack: bid<8192 -> mk [N][T][D] -> pa [n*16+tb][ks(8)][4096 u16] (32MB)
//              bid>=8192 -> Wm [H][256e][256d] -> pb [h*2+eb][ks(8)][4096 u16] (1MB)
__global__ void k_pack(const float* __restrict__ mk, const float* __restrict__ wm,
                       u16* __restrict__ pa, u16* __restrict__ pb) {
  const int bid = blockIdx.x;
  if (bid < 8192) {
    int u = bid * 256 + threadIdx.x;
    int pos  = u & 7;
    int line = (u >> 3) & 63;
    int ks   = (u >> 9) & 7;
    int tb   = (u >> 12) & 15;
    int n    = u >> 16;
    int origpos = pos ^ (line & 7);
    int r   = (line << 1) + (origpos >> 2);
    int ksl = origpos & 3;
    int kb  = (ks << 5) + (ksl << 2);
    const float* src = mk + (((size_t)n * TT + (tb << 7) + r) << 8) + kb;
    f4 v0 = *(const f4*)src;
    f4 v1 = *(const f4*)(src + 16);
    u16 hv[8] = {f2h(v0.x), f2h(v0.y), f2h(v0.z), f2h(v0.w),
                 f2h(v1.x), f2h(v1.y), f2h(v1.z), f2h(v1.w)};
    *(u16x8*)(pa + ((size_t)u << 3)) = *(u16x8*)hv;
  } else {
    int u = (bid - 8192) * 256 + threadIdx.x;
    int pos  = u & 7;
    int line = (u >> 3) & 63;
    int ks   = (u >> 9) & 7;
    int eb   = (u >> 12) & 1;
    int h    = u >> 13;
    int origpos = pos ^ (line & 7);
    int el  = (line << 1) + (origpos >> 2);
    int e   = (eb << 7) + el;
    int ksl = origpos & 3;
    int kb  = (ks << 5) + (ksl << 2);
    const float* src = wm + (((size_t)h * 256 + e) << 8) + kb;
    f4 v0 = *(const f4*)src;
    f4 v1 = *(const f4*)(src + 16);
    u16 hv[8] = {f2h(v0.x), f2h(v0.y), f2h(v0.z), f2h(v0.w),
                 f2h(v1.x), f2h(v1.y), f2h(v1.z), f2h(v1.w)};
    *(u16x8*)(pb + ((size_t)u << 3)) = *(u16x8*)hv;
  }
}

// ---------------------------------------------------------------------------
// sc2[(h*32+n)*2+eb][t] = sum_{e in eb-half} tanh(Wm[h] @ mk[n,t])[e] * ok[n,e]
// SWAPPED operands: A=Wm (M=e 128), B=mk (N=t 128) -> acc = P^T[e][t].
// Epilogue dot over e done with a SECOND MFMA (acc regs are lane-local
// B-operand k-fragments); no shfl-reduce.
// Double-buffered LDS, stage(k+1) issued before compute(k): 1 barrier/step.
// ---------------------------------------------------------------------------
__global__ __launch_bounds__(256, 3) void k_scoresf(
    const float* __restrict__ ok, const u16* __restrict__ pa,
    const u16* __restrict__ pb, float* __restrict__ sc2) {
  __shared__ __align__(1024) u16 lds[2][8192];  // 2 x (mk 8KB | Wm 8KB)
  __shared__ float red[128][2];

  const int bid = blockIdx.x;
  const int h  = bid & 7;            // == XCD
  const int eb = (bid >> 3) & 1;
  const int tb = (bid >> 4) & 15;
  const int n  = bid >> 8;
  const int tid = threadIdx.x;
  const int wave = tid >> 6;
  const int lane = tid & 63;
  const int wr = wave >> 1, wc = wave & 1;   // wr: e-half, wc: t-half
  const int l15 = lane & 15, lg = lane >> 4;

  // fragment LDS offsets (u16 units): Wm = A operand (rows e), mk = B (rows t)
  int Woff[4], Moff[4];
#pragma unroll
  for (int mi = 0; mi < 4; ++mi) {
    int row = (wr << 6) + (mi << 4) + l15;
    int line = row >> 1;
    int pos = (lg | ((row & 1) << 2)) ^ (line & 7);
    Woff[mi] = 4096 + (line << 6) + (pos << 3);
  }
#pragma unroll
  for (int ni = 0; ni < 4; ++ni) {
    int row = (wc << 6) + (ni << 4) + l15;
    int line = row >> 1;
    int pos = (lg | ((row & 1) << 2)) ^ (line & 7);
    Moff[ni] = (line << 6) + (pos << 3);
  }

  const u16* abase = pa + ((size_t)(n * 16 + tb) << 15);
  const u16* bbase = pb + ((size_t)(h * 2 + eb) << 15);

  auto stage = [&](int ks, int cur) {
    u16* dst = &lds[cur][0];
#pragma unroll
    for (int j = 0; j < 4; ++j) {
      const int c = (j << 2) + wave;   // mk chunks 0..7, Wm chunks 8..15
      const u16* src = (j < 2 ? abase + (ks << 12) + (c << 9)
                              : bbase + (ks << 12) + ((c - 8) << 9)) + (lane << 3);
      gl_lds16(src, dst + (c << 9));
    }
  };

  f32x4 acc[4][4];
#pragma unroll
  for (int i = 0; i < 4; ++i)
#pragma unroll
    for (int j = 0; j < 4; ++j) acc[i][j] = (f32x4){0.f, 0.f, 0.f, 0.f};

  stage(0, 0);
  __syncthreads();                    // drains vmcnt(0)
#pragma unroll 1
  for (int ks = 0; ks < 8; ++ks) {
    const int cur = ks & 1;
    if (ks < 7) stage(ks + 1, cur ^ 1);   // overlap next-step loads w/ compute
    f16x8 wfr[4], mfr[4];
#pragma unroll
    for (int mi = 0; mi < 4; ++mi) wfr[mi] = *(const f16x8*)&lds[cur][Woff[mi]];
#pragma unroll
    for (int ni = 0; ni < 4; ++ni) mfr[ni] = *(const f16x8*)&lds[cur][Moff[ni]];
#pragma unroll
    for (int mi = 0; mi < 4; ++mi)
#pragma unroll
      for (int ni = 0; ni < 4; ++ni)
        acc[mi][ni] = __builtin_amdgcn_mfma_f32_16x16x32_f16(wfr[mi], mfr[ni], acc[mi][ni], 0, 0, 0);
    __syncthreads();                  // drains stage's vmcnt + sync reads
  }

  // Epilogue: S_partial[t] = sum_e tanh(P^T[e][t]) * ok[e]  via MFMA.
  // acc lane layout: e_row = mi*16 + lg*4 + j, t_col = l15 (verified C/D map).
  // B2 frag for (ni,q): elem b -> tanh(acc[2q+(b>>2)][ni][b&3]); k-pattern
  // k = lg*4 + (b&3) + 16*(b>>2) matches e rows lane-locally.
#pragma unroll
  for (int mi = 0; mi < 4; ++mi)
#pragma unroll
    for (int ni = 0; ni < 4; ++ni)
#pragma unroll
      for (int j = 0; j < 4; ++j) acc[mi][ni][j] = ftanh(acc[mi][ni][j]);

  // ok A-fragments (rows replicated): elem b -> ok[e_base + q*32 + lg*4 + (b&3) + 16*(b>>2)]
  f16x8 a2[2];
#pragma unroll
  for (int q = 0; q < 2; ++q) {
    const float* okb = ok + (n << 8) + (eb << 7) + (wr << 6) + (q << 5) + (lg << 2);
#pragma unroll
    for (int b = 0; b < 8; ++b)
      a2[q][b] = (_Float16)okb[(b & 3) + ((b >> 2) << 4)];
  }

  f32x4 d2[4];
#pragma unroll
  for (int ni = 0; ni < 4; ++ni) d2[ni] = (f32x4){0.f, 0.f, 0.f, 0.f};
#pragma unroll
  for (int ni = 0; ni < 4; ++ni) {
#pragma unroll
    for (int q = 0; q < 2; ++q) {
      f16x8 b2;
#pragma unroll
      for (int b = 0; b < 8; ++b)
        b2[b] = (_Float16)acc[2 * q + (b >> 2)][ni][b & 3];
      d2[ni] = __builtin_amdgcn_mfma_f32_16x16x32_f16(a2[q], b2, d2[ni], 0, 0, 0);
    }
  }

  // All D2 rows equal; lane holds S[t = t_half + ni*16 + l15] in d2[ni][0].
  if (lg == 0) {
#pragma unroll
    for (int ni = 0; ni < 4; ++ni)
      red[(wc << 6) + (ni << 4) + l15][wr] = d2[ni][0];
  }
  __syncthreads();
  if (tid < 128) {
    float v = red[tid][0] + red[tid][1];
    sc2[((size_t)((h * 32 + n) * 2 + eb) << 11) + (tb << 7) + tid] = v;
  }
}

// ---------------------------------------------------------------------------
// Softmax over T per (h,n) row: adds the two eb partials, result -> eb=0 slot.
// ---------------------------------------------------------------------------
__global__ void k_softmax(float* __restrict__ sc2) {
  __shared__ float sm[8];
  const int row = blockIdx.x, tid = threadIdx.x;
  float* b0 = sc2 + ((size_t)row << 12);
  const float* b1 = b0 + 2048;
  f4 a = *(const f4*)(b0 + tid * 8);
  f4 b = *(const f4*)(b0 + tid * 8 + 4);
  f4 a1 = *(const f4*)(b1 + tid * 8);
  f4 b1v = *(const f4*)(b1 + tid * 8 + 4);
  a.x += a1.x; a.y += a1.y; a.z += a1.z; a.w += a1.w;
  b.x += b1v.x; b.y += b1v.y; b.z += b1v.z; b.w += b1v.w;
  float m = fmaxf(fmaxf(fmaxf(a.x, a.y), fmaxf(a.z, a.w)),
                  fmaxf(fmaxf(b.x, b.y), fmaxf(b.z, b.w)));
#pragma unroll
  for (int o = 1; o < 64; o <<= 1) m = fmaxf(m, __shfl_xor(m, o));
  if ((tid & 63) == 0) sm[tid >> 6] = m;
  __syncthreads();
  m = fmaxf(fmaxf(sm[0], sm[1]), fmaxf(sm[2], sm[3]));
  a.x = __expf(a.x - m); a.y = __expf(a.y - m); a.z = __expf(a.z - m); a.w = __expf(a.w - m);
  b.x = __expf(b.x - m); b.y = __expf(b.y - m); b.z = __expf(b.z - m); b.w = __expf(b.w - m);
  float s = a.x + a.y + a.z + a.w + b.x + b.y + b.z + b.w;
#pragma unroll
  for (int o = 1; o < 64; o <<= 1) s += __shfl_xor(s, o);
  if ((tid & 63) == 0) sm[4 + (tid >> 6)] = s;
  __syncthreads();
  s = sm[4] + sm[5] + sm[6] + sm[7];
  float inv = 1.f / s;
  a.x *= inv; a.y *= inv; a.z *= inv; a.w *= inv;
  b.x *= inv; b.y *= inv; b.z *= inv; b.w *= inv;
  *(f4*)(b0 + tid * 8) = a;
  *(f4*)(b0 + tid * 8 + 4) = b;
}

// ---------------------------------------------------------------------------
// Partial rep over t-slices of 128: rp[n][sl][h*256+d]; probs at stride 4096.
// ---------------------------------------------------------------------------
__global__ void k_rep(const float* __restrict__ mv, const float* __restrict__ p,
                      float* __restrict__ rp) {
  __shared__ float pl[8][128];
  const int b = blockIdx.x;
  const int n = b >> 4, sl = b & 15;
  const int tid = threadIdx.x;
  for (int i = tid; i < 1024; i += 256) {
    int h = i >> 7, t = i & 127;
    pl[h][t] = p[(((size_t)h * 32 + n) << 12) + sl * 128 + t];
  }
  __syncthreads();
  float r[8] = {0.f, 0.f, 0.f, 0.f, 0.f, 0.f, 0.f, 0.f};
  const float* src = mv + (((size_t)n << 11) + sl * 128) * DD + tid;
#pragma unroll 4
  for (int tt = 0; tt < 128; ++tt) {
    float v = src[(size_t)tt * DD];
#pragma unroll
    for (int h = 0; h < 8; ++h) r[h] = fmaf(pl[h][tt], v, r[h]);
  }
  float* dst = rp + (((size_t)n * 16 + sl) << 11) + tid;
#pragma unroll
  for (int h = 0; h < 8; ++h) dst[h * 256] = r[h];
}

// ---------------------------------------------------------------------------
// out[n][i] = b[i] + sum_j concat[n][j] * Wo_w[i][j]
// ---------------------------------------------------------------------------
__global__ void k_out(const float* __restrict__ rp, const float* __restrict__ w,
                      const float* __restrict__ bias, float* __restrict__ out) {
  __shared__ float c[2048];
  const int n = blockIdx.x, tid = threadIdx.x;
  for (int j = tid; j < 2048; j += 256) {
    float s = 0.f;
#pragma unroll
    for (int sl = 0; sl < 16; ++sl) s += rp[(((size_t)n * 16 + sl) << 11) + j];
    c[j] = s;
  }
  __syncthreads();
  float acc = bias[tid];
  const f4* wrow = (const f4*)(w + (size_t)tid * 2048);
  const f4* cc = (const f4*)c;
  for (int j = 0; j < 512; ++j) {
    f4 wv = wrow[j];
    f4 cv = cc[j];
    acc += wv.x * cv.x + wv.y * cv.y + wv.z * cv.z + wv.w * cv.w;
  }
  out[n * 256 + tid] = acc;
}

extern "C" void kernel_launch(void* const* d_in, const int* in_sizes, int n_in,
                              void* d_out, int out_size, void* d_ws, size_t ws_size,
                              hipStream_t stream) {
  const float* ok  = (const float*)d_in[0];
  const float* mk  = (const float*)d_in[1];
  const float* mv  = (const float*)d_in[2];
  const float* wm  = (const float*)d_in[3];
  const float* wow = (const float*)d_in[4];
  const float* wob = (const float*)d_in[5];
  float* out = (float*)d_out;
  char* ws = (char*)d_ws;

  // ws: [0,4MB) sc2 partials/probs | [4,5MB) packB | [8,16MB) rep | [16,48MB) packA
  float* sc2 = (float*)ws;
  u16* pb    = (u16*)(ws + (4u << 20));
  float* rp  = (float*)(ws + (8u << 20));
  u16* pa    = (u16*)(ws + (16u << 20));

  hipLaunchKernelGGL(k_pack,    dim3(8448), dim3(256), 0, stream, mk, wm, pa, pb);
  hipLaunchKernelGGL(k_scoresf, dim3(8192), dim3(256), 0, stream, ok, pa, pb, sc2);
  hipLaunchKernelGGL(k_softmax, dim3(256),  dim3(256), 0, stream, sc2);
  hipLaunchKernelGGL(k_rep,     dim3(512),  dim3(256), 0, stream, mv, sc2, rp);
  hipLaunchKernelGGL(k_out,     dim3(32),   dim3(256), 0, stream, rp, wow, wob, out);
}

// Round 11
// 199.929 us; speedup vs baseline: 1.1109x; 1.1109x over previous
//
#include <hip/hip_runtime.h>

#define HH 8
#define NN 32
#define TT 2048
#define DD 256

typedef float f4 __attribute__((ext_vector_type(4)));
typedef float f32x4 __attribute__((ext_vector_type(4)));
typedef _Float16 f16x8 __attribute__((ext_vector_type(8)));
typedef unsigned short u16;
typedef u16 u16x8 __attribute__((ext_vector_type(8)));

__device__ __forceinline__ u16 f2h(float x) {
  _Float16 h = (_Float16)x;
  return *(u16*)&h;
}

// Fast tanh: t = fma(-2, rcp(exp(2|x|)+1), 1), sign via copysign.
// 2 trans + 4 full-rate VALU. Overflow-safe (rcp(inf)=0 -> t=1).
__device__ __forceinline__ float ftanh(float x) {
  float ax = __builtin_fabsf(x);
  float e = __expf(ax + ax);
  float r = __builtin_amdgcn_rcpf(e + 1.f);
  float t = __builtin_fmaf(-2.f, r, 1.f);
  return __builtin_copysignf(t, x);
}

__device__ __forceinline__ void gl_lds16(const void* g, void* l) {
  __builtin_amdgcn_global_load_lds((const __attribute__((address_space(1))) unsigned*)g,
                                   (__attribute__((address_space(3))) unsigned*)l, 16, 0, 0);
}

// ===========================================================================
// Packed operand layout (verified R2-R10), 128-row regions:
// per 8KB region = [128 rows][32 k] f16:
//   line = row>>1 (128B lines of 8 x 16B slots), line in [0,64);
//   slot pos = (ksl | ((row&1)<<2)) ^ (line&7)   (XOR bank swizzle);
//   within slot, u16 j holds k = ks*32 + ksl*4 + {0,1,2,3,16,17,18,19}[j]
//   (k-pattern of mfma_f32_16x16x32 operand fragments).
// ===========================================================================

// Merged pack: bid<8192 -> mk [N][T][D] -> pa [n*16+tb][ks(8)][4096 u16] (32MB)
//              bid>=8192 -> Wm [H][256e][256d] -> pb [h*2+eb][ks(8)][4096 u16] (1MB)
__global__ void k_pack(const float* __restrict__ mk, const float* __restrict__ wm,
                       u16* __restrict__ pa, u16* __restrict__ pb) {
  const int bid = blockIdx.x;
  if (bid < 8192) {
    int u = bid * 256 + threadIdx.x;
    int pos  = u & 7;
    int line = (u >> 3) & 63;
    int ks   = (u >> 9) & 7;
    int tb   = (u >> 12) & 15;
    int n    = u >> 16;
    int origpos = pos ^ (line & 7);
    int r   = (line << 1) + (origpos >> 2);
    int ksl = origpos & 3;
    int kb  = (ks << 5) + (ksl << 2);
    const float* src = mk + (((size_t)n * TT + (tb << 7) + r) << 8) + kb;
    f4 v0 = *(const f4*)src;
    f4 v1 = *(const f4*)(src + 16);
    u16 hv[8] = {f2h(v0.x), f2h(v0.y), f2h(v0.z), f2h(v0.w),
                 f2h(v1.x), f2h(v1.y), f2h(v1.z), f2h(v1.w)};
    *(u16x8*)(pa + ((size_t)u << 3)) = *(u16x8*)hv;
  } else {
    int u = (bid - 8192) * 256 + threadIdx.x;
    int pos  = u & 7;
    int line = (u >> 3) & 63;
    int ks   = (u >> 9) & 7;
    int eb   = (u >> 12) & 1;
    int h    = u >> 13;
    int origpos = pos ^ (line & 7);
    int el  = (line << 1) + (origpos >> 2);
    int e   = (eb << 7) + el;
    int ksl = origpos & 3;
    int kb  = (ks << 5) + (ksl << 2);
    const float* src = wm + (((size_t)h * 256 + e) << 8) + kb;
    f4 v0 = *(const f4*)src;
    f4 v1 = *(const f4*)(src + 16);
    u16 hv[8] = {f2h(v0.x), f2h(v0.y), f2h(v0.z), f2h(v0.w),
                 f2h(v1.x), f2h(v1.y), f2h(v1.z), f2h(v1.w)};
    *(u16x8*)(pb + ((size_t)u << 3)) = *(u16x8*)hv;
  }
}

// ---------------------------------------------------------------------------
// sc2[(h*32+n)*2+eb][t] = sum_{e in eb-half} tanh(Wm[h] @ mk[n,t])[e] * ok[n,e]
// A=Wm (M=e 128), B=mk (N=t 128) -> acc = P^T[e][t]; o_k dot via 2nd MFMA.
// NEW (R11): 3-buffer depth-2 prefetch with COUNTED vmcnt (T3+T4): never
// drain vmcnt to 0 in the loop. 2 raw barriers/step; sched_barrier pins.
// ---------------------------------------------------------------------------
__global__ __launch_bounds__(256, 3) void k_scoresf(
    const float* __restrict__ ok, const u16* __restrict__ pa,
    const u16* __restrict__ pb, float* __restrict__ sc2) {
  __shared__ __align__(1024) u16 lds[3 * 8192];  // 3 bufs x (mk 8KB | Wm 8KB)
  __shared__ float red[128][2];

  const int bid = blockIdx.x;
  const int h  = bid & 7;            // == XCD
  const int eb = (bid >> 3) & 1;
  const int tb = (bid >> 4) & 15;
  const int n  = bid >> 8;
  const int tid = threadIdx.x;
  const int wave = tid >> 6;
  const int lane = tid & 63;
  const int wr = wave >> 1, wc = wave & 1;   // wr: e-half, wc: t-half
  const int l15 = lane & 15, lg = lane >> 4;

  // fragment LDS offsets (u16 units, within one 8192-u16 buffer)
  int Woff[4], Moff[4];
#pragma unroll
  for (int mi = 0; mi < 4; ++mi) {
    int row = (wr << 6) + (mi << 4) + l15;
    int line = row >> 1;
    int pos = (lg | ((row & 1) << 2)) ^ (line & 7);
    Woff[mi] = 4096 + (line << 6) + (pos << 3);
  }
#pragma unroll
  for (int ni = 0; ni < 4; ++ni) {
    int row = (wc << 6) + (ni << 4) + l15;
    int line = row >> 1;
    int pos = (lg | ((row & 1) << 2)) ^ (line & 7);
    Moff[ni] = (line << 6) + (pos << 3);
  }

  const u16* abase = pa + ((size_t)(n * 16 + tb) << 15);
  const u16* bbase = pb + ((size_t)(h * 2 + eb) << 15);

  auto stage = [&](int ks, int buf) {
    u16* dst = &lds[buf << 13];
#pragma unroll
    for (int j = 0; j < 4; ++j) {
      const int c = (j << 2) + wave;   // mk chunks 0..7, Wm chunks 8..15
      const u16* src = (j < 2 ? abase + (ks << 12) + (c << 9)
                              : bbase + (ks << 12) + ((c - 8) << 9)) + (lane << 3);
      gl_lds16(src, dst + (c << 9));
    }
  };

  f32x4 acc[4][4];
#pragma unroll
  for (int i = 0; i < 4; ++i)
#pragma unroll
    for (int j = 0; j < 4; ++j) acc[i][j] = (f32x4){0.f, 0.f, 0.f, 0.f};

  stage(0, 0);
  stage(1, 1);

  // One K-step: counted wait for stage(ks) (VMC = 4*stages-in-flight-after),
  // barrier, read buf, 16 MFMA, barrier. Reads complete before BAR2 (MFMA
  // lgkm consumption), so next step's stage can safely overwrite buf+2.
#define STEP(CUR, VMC)                                                          \
  do {                                                                          \
    asm volatile("s_waitcnt vmcnt(" #VMC ")" ::: "memory");                     \
    __builtin_amdgcn_s_barrier();                                               \
    __builtin_amdgcn_sched_barrier(0);                                          \
    const u16* buf = &lds[(CUR) << 13];                                         \
    f16x8 wfr[4], mfr[4];                                                       \
    _Pragma("unroll") for (int mi = 0; mi < 4; ++mi)                            \
        wfr[mi] = *(const f16x8*)(buf + Woff[mi]);                              \
    _Pragma("unroll") for (int ni = 0; ni < 4; ++ni)                            \
        mfr[ni] = *(const f16x8*)(buf + Moff[ni]);                              \
    _Pragma("unroll") for (int mi = 0; mi < 4; ++mi)                            \
        _Pragma("unroll") for (int ni = 0; ni < 4; ++ni)                        \
            acc[mi][ni] = __builtin_amdgcn_mfma_f32_16x16x32_f16(               \
                wfr[mi], mfr[ni], acc[mi][ni], 0, 0, 0);                        \
    __builtin_amdgcn_sched_barrier(0);                                          \
    __builtin_amdgcn_s_barrier();                                               \
  } while (0)

  {
    int cur = 0;
#pragma unroll 1
    for (int ks = 0; ks < 6; ++ks) {
      int nxt2 = cur + 2 >= 3 ? cur - 1 : cur + 2;
      stage(ks + 2, nxt2);
      STEP(cur, 8);
      cur = cur == 2 ? 0 : cur + 1;
    }
    // ks=6: buf 0 (6%3); ks=7: buf 1
    STEP(0, 4);
    STEP(1, 0);
  }
#undef STEP

  // Epilogue: S_partial[t] = sum_e tanh(P^T[e][t]) * ok[e] via 2nd MFMA.
  // acc lane layout: e_row = mi*16 + lg*4 + j, t_col = l15.
#pragma unroll
  for (int mi = 0; mi < 4; ++mi)
#pragma unroll
    for (int ni = 0; ni < 4; ++ni)
#pragma unroll
      for (int j = 0; j < 4; ++j) acc[mi][ni][j] = ftanh(acc[mi][ni][j]);

  f16x8 a2[2];
#pragma unroll
  for (int q = 0; q < 2; ++q) {
    const float* okb = ok + (n << 8) + (eb << 7) + (wr << 6) + (q << 5) + (lg << 2);
#pragma unroll
    for (int b = 0; b < 8; ++b)
      a2[q][b] = (_Float16)okb[(b & 3) + ((b >> 2) << 4)];
  }

  f32x4 d2[4];
#pragma unroll
  for (int ni = 0; ni < 4; ++ni) d2[ni] = (f32x4){0.f, 0.f, 0.f, 0.f};
#pragma unroll
  for (int ni = 0; ni < 4; ++ni) {
#pragma unroll
    for (int q = 0; q < 2; ++q) {
      f16x8 b2;
#pragma unroll
      for (int b = 0; b < 8; ++b)
        b2[b] = (_Float16)acc[2 * q + (b >> 2)][ni][b & 3];
      d2[ni] = __builtin_amdgcn_mfma_f32_16x16x32_f16(a2[q], b2, d2[ni], 0, 0, 0);
    }
  }

  if (lg == 0) {
#pragma unroll
    for (int ni = 0; ni < 4; ++ni)
      red[(wc << 6) + (ni << 4) + l15][wr] = d2[ni][0];
  }
  __syncthreads();
  if (tid < 128) {
    float v = red[tid][0] + red[tid][1];
    sc2[((size_t)((h * 32 + n) * 2 + eb) << 11) + (tb << 7) + tid] = v;
  }
}

// ---------------------------------------------------------------------------
// Softmax over T per (h,n) row: adds the two eb partials, result -> eb=0 slot.
// ---------------------------------------------------------------------------
__global__ void k_softmax(float* __restrict__ sc2) {
  __shared__ float sm[8];
  const int row = blockIdx.x, tid = threadIdx.x;
  float* b0 = sc2 + ((size_t)row << 12);
  const float* b1 = b0 + 2048;
  f4 a = *(const f4*)(b0 + tid * 8);
  f4 b = *(const f4*)(b0 + tid * 8 + 4);
  f4 a1 = *(const f4*)(b1 + tid * 8);
  f4 b1v = *(const f4*)(b1 + tid * 8 + 4);
  a.x += a1.x; a.y += a1.y; a.z += a1.z; a.w += a1.w;
  b.x += b1v.x; b.y += b1v.y; b.z += b1v.z; b.w += b1v.w;
  float m = fmaxf(fmaxf(fmaxf(a.x, a.y), fmaxf(a.z, a.w)),
                  fmaxf(fmaxf(b.x, b.y), fmaxf(b.z, b.w)));
#pragma unroll
  for (int o = 1; o < 64; o <<= 1) m = fmaxf(m, __shfl_xor(m, o));
  if ((tid & 63) == 0) sm[tid >> 6] = m;
  __syncthreads();
  m = fmaxf(fmaxf(sm[0], sm[1]), fmaxf(sm[2], sm[3]));
  a.x = __expf(a.x - m); a.y = __expf(a.y - m); a.z = __expf(a.z - m); a.w = __expf(a.w - m);
  b.x = __expf(b.x - m); b.y = __expf(b.y - m); b.z = __expf(b.z - m); b.w = __expf(b.w - m);
  float s = a.x + a.y + a.z + a.w + b.x + b.y + b.z + b.w;
#pragma unroll
  for (int o = 1; o < 64; o <<= 1) s += __shfl_xor(s, o);
  if ((tid & 63) == 0) sm[4 + (tid >> 6)] = s;
  __syncthreads();
  s = sm[4] + sm[5] + sm[6] + sm[7];
  float inv = 1.f / s;
  a.x *= inv; a.y *= inv; a.z *= inv; a.w *= inv;
  b.x *= inv; b.y *= inv; b.z *= inv; b.w *= inv;
  *(f4*)(b0 + tid * 8) = a;
  *(f4*)(b0 + tid * 8 + 4) = b;
}

// ---------------------------------------------------------------------------
// Partial rep over t-slices of 128: rp[n][sl][h*256+d]; probs at stride 4096.
// ---------------------------------------------------------------------------
__global__ void k_rep(const float* __restrict__ mv, const float* __restrict__ p,
                      float* __restrict__ rp) {
  __shared__ float pl[8][128];
  const int b = blockIdx.x;
  const int n = b >> 4, sl = b & 15;
  const int tid = threadIdx.x;
  for (int i = tid; i < 1024; i += 256) {
    int h = i >> 7, t = i & 127;
    pl[h][t] = p[(((size_t)h * 32 + n) << 12) + sl * 128 + t];
  }
  __syncthreads();
  float r[8] = {0.f, 0.f, 0.f, 0.f, 0.f, 0.f, 0.f, 0.f};
  const float* src = mv + (((size_t)n << 11) + sl * 128) * DD + tid;
#pragma unroll 4
  for (int tt = 0; tt < 128; ++tt) {
    float v = src[(size_t)tt * DD];
#pragma unroll
    for (int h = 0; h < 8; ++h) r[h] = fmaf(pl[h][tt], v, r[h]);
  }
  float* dst = rp + (((size_t)n * 16 + sl) << 11) + tid;
#pragma unroll
  for (int h = 0; h < 8; ++h) dst[h * 256] = r[h];
}

// ---------------------------------------------------------------------------
// out[n][i] = b[i] + sum_j concat[n][j] * Wo_w[i][j]
// ---------------------------------------------------------------------------
__global__ void k_out(const float* __restrict__ rp, const float* __restrict__ w,
                      const float* __restrict__ bias, float* __restrict__ out) {
  __shared__ float c[2048];
  const int n = blockIdx.x, tid = threadIdx.x;
  for (int j = tid; j < 2048; j += 256) {
    float s = 0.f;
#pragma unroll
    for (int sl = 0; sl < 16; ++sl) s += rp[(((size_t)n * 16 + sl) << 11) + j];
    c[j] = s;
  }
  __syncthreads();
  float acc = bias[tid];
  const f4* wrow = (const f4*)(w + (size_t)tid * 2048);
  const f4* cc = (const f4*)c;
  for (int j = 0; j < 512; ++j) {
    f4 wv = wrow[j];
    f4 cv = cc[j];
    acc += wv.x * cv.x + wv.y * cv.y + wv.z * cv.z + wv.w * cv.w;
  }
  out[n * 256 + tid] = acc;
}

extern "C" void kernel_launch(void* const* d_in, const int* in_sizes, int n_in,
                              void* d_out, int out_size, void* d_ws, size_t ws_size,
                              hipStream_t stream) {
  const float* ok  = (const float*)d_in[0];
  const float* mk  = (const float*)d_in[1];
  const float* mv  = (const float*)d_in[2];
  const float* wm  = (const float*)d_in[3];
  const float* wow = (const float*)d_in[4];
  const float* wob = (const float*)d_in[5];
  float* out = (float*)d_out;
  char* ws = (char*)d_ws;

  // ws: [0,4MB) sc2 partials/probs | [4,5MB) packB | [8,16MB) rep | [16,48MB) packA
  float* sc2 = (float*)ws;
  u16* pb    = (u16*)(ws + (4u << 20));
  float* rp  = (float*)(ws + (8u << 20));
  u16* pa    = (u16*)(ws + (16u << 20));

  hipLaunchKernelGGL(k_pack,    dim3(8448), dim3(256), 0, stream, mk, wm, pa, pb);
  hipLaunchKernelGGL(k_scoresf, dim3(8192), dim3(256), 0, stream, ok, pa, pb, sc2);
  hipLaunchKernelGGL(k_softmax, dim3(256),  dim3(256), 0, stream, sc2);
  hipLaunchKernelGGL(k_rep,     dim3(512),  dim3(256), 0, stream, mv, sc2, rp);
  hipLaunchKernelGGL(k_out,     dim3(32),   dim3(256), 0, stream, rp, wow, wob, out);
}

// Round 13
// 193.143 us; speedup vs baseline: 1.1499x; 1.0351x over previous
//
#include <hip/hip_runtime.h>

#define HH 8
#define NN 32
#define TT 2048
#define DD 256

typedef float f4 __attribute__((ext_vector_type(4)));
typedef float f32x4 __attribute__((ext_vector_type(4)));
typedef _Float16 f16x8 __attribute__((ext_vector_type(8)));
typedef __fp16 fp16x2 __attribute__((ext_vector_type(2)));   // cvt_pkrtz return type
typedef unsigned short u16;
typedef u16 u16x8 __attribute__((ext_vector_type(8)));

__device__ __forceinline__ u16 f2h(float x) {
  _Float16 h = (_Float16)x;
  return *(u16*)&h;
}

// Fast tanh, valid for ALL x without abs/copysign:
// tanh(x) = 1 - 2/(exp(2x)+1).  x->-inf: 1-2 = -1; x->+inf: 1-0 = +1.
// 2 trans (v_exp, v_rcp) + 3 full-rate.
__device__ __forceinline__ float ftanh(float x) {
  float e = __expf(x + x);
  float r = __builtin_amdgcn_rcpf(e + 1.f);
  return __builtin_fmaf(-2.f, r, 1.f);
}

__device__ __forceinline__ void gl_lds16(const void* g, void* l) {
  __builtin_amdgcn_global_load_lds((const __attribute__((address_space(1))) unsigned*)g,
                                   (__attribute__((address_space(3))) unsigned*)l, 16, 0, 0);
}

// ===========================================================================
// Packed operand layout (verified R2-R11), 128-row regions:
// per 8KB region = [128 rows][32 k] f16:
//   line = row>>1 (128B lines of 8 x 16B slots), line in [0,64);
//   slot pos = (ksl | ((row&1)<<2)) ^ (line&7)   (XOR bank swizzle);
//   within slot, u16 j holds k = ks*32 + ksl*4 + {0,1,2,3,16,17,18,19}[j]
//   (k-pattern of mfma_f32_16x16x32 operand fragments).
// ===========================================================================

// Merged pack: bid<8192 -> mk [N][T][D] -> pa [n*16+tb][ks(8)][4096 u16] (32MB)
//              bid>=8192 -> Wm [H][256e][256d] -> pb [h*2+eb][ks(8)][4096 u16] (1MB)
__global__ void k_pack(const float* __restrict__ mk, const float* __restrict__ wm,
                       u16* __restrict__ pa, u16* __restrict__ pb) {
  const int bid = blockIdx.x;
  if (bid < 8192) {
    int u = bid * 256 + threadIdx.x;
    int pos  = u & 7;
    int line = (u >> 3) & 63;
    int ks   = (u >> 9) & 7;
    int tb   = (u >> 12) & 15;
    int n    = u >> 16;
    int origpos = pos ^ (line & 7);
    int r   = (line << 1) + (origpos >> 2);
    int ksl = origpos & 3;
    int kb  = (ks << 5) + (ksl << 2);
    const float* src = mk + (((size_t)n * TT + (tb << 7) + r) << 8) + kb;
    f4 v0 = *(const f4*)src;
    f4 v1 = *(const f4*)(src + 16);
    u16 hv[8] = {f2h(v0.x), f2h(v0.y), f2h(v0.z), f2h(v0.w),
                 f2h(v1.x), f2h(v1.y), f2h(v1.z), f2h(v1.w)};
    *(u16x8*)(pa + ((size_t)u << 3)) = *(u16x8*)hv;
  } else {
    int u = (bid - 8192) * 256 + threadIdx.x;
    int pos  = u & 7;
    int line = (u >> 3) & 63;
    int ks   = (u >> 9) & 7;
    int eb   = (u >> 12) & 1;
    int h    = u >> 13;
    int origpos = pos ^ (line & 7);
    int el  = (line << 1) + (origpos >> 2);
    int e   = (eb << 7) + el;
    int ksl = origpos & 3;
    int kb  = (ks << 5) + (ksl << 2);
    const float* src = wm + (((size_t)h * 256 + e) << 8) + kb;
    f4 v0 = *(const f4*)src;
    f4 v1 = *(const f4*)(src + 16);
    u16 hv[8] = {f2h(v0.x), f2h(v0.y), f2h(v0.z), f2h(v0.w),
                 f2h(v1.x), f2h(v1.y), f2h(v1.z), f2h(v1.w)};
    *(u16x8*)(pb + ((size_t)u << 3)) = *(u16x8*)hv;
  }
}

// ---------------------------------------------------------------------------
// sc2[(h*32+n)*2+eb][t] = sum_{e in eb-half} tanh(Wm[h] @ mk[n,t])[e] * ok[n,e]
// A=Wm (M=e 128), B=mk (N=t 128) -> acc = P^T[e][t]; o_k dot via 2nd MFMA.
// R11: 3-buffer depth-2 counted-vmcnt pipeline. R12: fully unrolled K-loop
// (compile-time stage addresses), setprio around MFMA, cheaper tanh/cvt.
// ---------------------------------------------------------------------------
__global__ __launch_bounds__(256, 3) void k_scoresf(
    const float* __restrict__ ok, const u16* __restrict__ pa,
    const u16* __restrict__ pb, float* __restrict__ sc2) {
  __shared__ __align__(1024) u16 lds[3 * 8192];  // 3 bufs x (mk 8KB | Wm 8KB)
  __shared__ float red[128][2];

  const int bid = blockIdx.x;
  const int h  = bid & 7;            // == XCD
  const int eb = (bid >> 3) & 1;
  const int tb = (bid >> 4) & 15;
  const int n  = bid >> 8;
  const int tid = threadIdx.x;
  const int wave = tid >> 6;
  const int lane = tid & 63;
  const int wr = wave >> 1, wc = wave & 1;   // wr: e-half, wc: t-half
  const int l15 = lane & 15, lg = lane >> 4;

  // fragment LDS offsets (u16 units, within one 8192-u16 buffer)
  int Woff[4], Moff[4];
#pragma unroll
  for (int mi = 0; mi < 4; ++mi) {
    int row = (wr << 6) + (mi << 4) + l15;
    int line = row >> 1;
    int pos = (lg | ((row & 1) << 2)) ^ (line & 7);
    Woff[mi] = 4096 + (line << 6) + (pos << 3);
  }
#pragma unroll
  for (int ni = 0; ni < 4; ++ni) {
    int row = (wc << 6) + (ni << 4) + l15;
    int line = row >> 1;
    int pos = (lg | ((row & 1) << 2)) ^ (line & 7);
    Moff[ni] = (line << 6) + (pos << 3);
  }

  const u16* abase = pa + ((size_t)(n * 16 + tb) << 15);
  const u16* bbase = pb + ((size_t)(h * 2 + eb) << 15);

  f32x4 acc[4][4];
#pragma unroll
  for (int i = 0; i < 4; ++i)
#pragma unroll
    for (int j = 0; j < 4; ++j) acc[i][j] = (f32x4){0.f, 0.f, 0.f, 0.f};

  // STAGE(KS, BUF): compile-time constants -> address CSE, minimal VALU.
#define STAGE(KS, BUF)                                                          \
  do {                                                                          \
    u16* dst = &lds[(BUF) << 13];                                               \
    _Pragma("unroll") for (int j = 0; j < 4; ++j) {                             \
      const int c = (j << 2) + wave;                                           \
      const u16* src = (j < 2 ? abase + ((KS) << 12) + (c << 9)                 \
                              : bbase + ((KS) << 12) + ((c - 8) << 9)) +        \
                       (lane << 3);                                             \
      gl_lds16(src, dst + (c << 9));                                            \
    }                                                                           \
  } while (0)

  // STEP(BUF, VMC): counted wait, barrier, ds_read frags, 16 MFMA, barrier.
#define STEP(BUF, VMC)                                                          \
  do {                                                                          \
    asm volatile("s_waitcnt vmcnt(" #VMC ")" ::: "memory");                     \
    __builtin_amdgcn_s_barrier();                                               \
    __builtin_amdgcn_sched_barrier(0);                                          \
    const u16* buf = &lds[(BUF) << 13];                                         \
    f16x8 wfr[4], mfr[4];                                                       \
    _Pragma("unroll") for (int mi = 0; mi < 4; ++mi)                            \
        wfr[mi] = *(const f16x8*)(buf + Woff[mi]);                              \
    _Pragma("unroll") for (int ni = 0; ni < 4; ++ni)                            \
        mfr[ni] = *(const f16x8*)(buf + Moff[ni]);                              \
    __builtin_amdgcn_s_setprio(1);                                              \
    _Pragma("unroll") for (int mi = 0; mi < 4; ++mi)                            \
        _Pragma("unroll") for (int ni = 0; ni < 4; ++ni)                        \
            acc[mi][ni] = __builtin_amdgcn_mfma_f32_16x16x32_f16(               \
                wfr[mi], mfr[ni], acc[mi][ni], 0, 0, 0);                        \
    __builtin_amdgcn_s_setprio(0);                                              \
    __builtin_amdgcn_sched_barrier(0);                                          \
    __builtin_amdgcn_s_barrier();                                               \
  } while (0)

  STAGE(0, 0);
  STAGE(1, 1);
  STAGE(2, 2); STEP(0, 8);   // ks=0 in buf0
  STAGE(3, 0); STEP(1, 8);   // ks=1 in buf1
  STAGE(4, 1); STEP(2, 8);   // ks=2 in buf2
  STAGE(5, 2); STEP(0, 8);   // ks=3 in buf0
  STAGE(6, 0); STEP(1, 8);   // ks=4 in buf1
  STAGE(7, 1); STEP(2, 8);   // ks=5 in buf2
  STEP(0, 4);                // ks=6 in buf0
  STEP(1, 0);                // ks=7 in buf1
#undef STEP
#undef STAGE

  // Epilogue: S_partial[t] = sum_e tanh(P^T[e][t]) * ok[e] via 2nd MFMA.
  // acc lane layout: e_row = mi*16 + lg*4 + j, t_col = l15.
#pragma unroll
  for (int mi = 0; mi < 4; ++mi)
#pragma unroll
    for (int ni = 0; ni < 4; ++ni)
#pragma unroll
      for (int j = 0; j < 4; ++j) acc[mi][ni][j] = ftanh(acc[mi][ni][j]);

  // ok A-fragments via pkrtz: elem b -> ok[ebase + q*32 + lg*4 + (b&3) + 16*(b>>2)]
  union F16x8 { f16x8 v; fp16x2 p[4]; };
  F16x8 a2[2];
#pragma unroll
  for (int q = 0; q < 2; ++q) {
    const float* okb = ok + (n << 8) + (eb << 7) + (wr << 6) + (q << 5) + (lg << 2);
    a2[q].p[0] = __builtin_amdgcn_cvt_pkrtz(okb[0], okb[1]);
    a2[q].p[1] = __builtin_amdgcn_cvt_pkrtz(okb[2], okb[3]);
    a2[q].p[2] = __builtin_amdgcn_cvt_pkrtz(okb[16], okb[17]);
    a2[q].p[3] = __builtin_amdgcn_cvt_pkrtz(okb[18], okb[19]);
  }

  f32x4 d2[4];
#pragma unroll
  for (int ni = 0; ni < 4; ++ni) d2[ni] = (f32x4){0.f, 0.f, 0.f, 0.f};
#pragma unroll
  for (int ni = 0; ni < 4; ++ni) {
#pragma unroll
    for (int q = 0; q < 2; ++q) {
      F16x8 b2;
      b2.p[0] = __builtin_amdgcn_cvt_pkrtz(acc[2 * q][ni][0], acc[2 * q][ni][1]);
      b2.p[1] = __builtin_amdgcn_cvt_pkrtz(acc[2 * q][ni][2], acc[2 * q][ni][3]);
      b2.p[2] = __builtin_amdgcn_cvt_pkrtz(acc[2 * q + 1][ni][0], acc[2 * q + 1][ni][1]);
      b2.p[3] = __builtin_amdgcn_cvt_pkrtz(acc[2 * q + 1][ni][2], acc[2 * q + 1][ni][3]);
      d2[ni] = __builtin_amdgcn_mfma_f32_16x16x32_f16(a2[q].v, b2.v, d2[ni], 0, 0, 0);
    }
  }

  if (lg == 0) {
#pragma unroll
    for (int ni = 0; ni < 4; ++ni)
      red[(wc << 6) + (ni << 4) + l15][wr] = d2[ni][0];
  }
  __syncthreads();
  if (tid < 128) {
    float v = red[tid][0] + red[tid][1];
    sc2[((size_t)((h * 32 + n) * 2 + eb) << 11) + (tb << 7) + tid] = v;
  }
}

// ---------------------------------------------------------------------------
// Softmax over T per (h,n) row: adds the two eb partials, result -> eb=0 slot.
// ---------------------------------------------------------------------------
__global__ void k_softmax(float* __restrict__ sc2) {
  __shared__ float sm[8];
  const int row = blockIdx.x, tid = threadIdx.x;
  float* b0 = sc2 + ((size_t)row << 12);
  const float* b1 = b0 + 2048;
  f4 a = *(const f4*)(b0 + tid * 8);
  f4 b = *(const f4*)(b0 + tid * 8 + 4);
  f4 a1 = *(const f4*)(b1 + tid * 8);
  f4 b1v = *(const f4*)(b1 + tid * 8 + 4);
  a.x += a1.x; a.y += a1.y; a.z += a1.z; a.w += a1.w;
  b.x += b1v.x; b.y += b1v.y; b.z += b1v.z; b.w += b1v.w;
  float m = fmaxf(fmaxf(fmaxf(a.x, a.y), fmaxf(a.z, a.w)),
                  fmaxf(fmaxf(b.x, b.y), fmaxf(b.z, b.w)));
#pragma unroll
  for (int o = 1; o < 64; o <<= 1) m = fmaxf(m, __shfl_xor(m, o));
  if ((tid & 63) == 0) sm[tid >> 6] = m;
  __syncthreads();
  m = fmaxf(fmaxf(sm[0], sm[1]), fmaxf(sm[2], sm[3]));
  a.x = __expf(a.x - m); a.y = __expf(a.y - m); a.z = __expf(a.z - m); a.w = __expf(a.w - m);
  b.x = __expf(b.x - m); b.y = __expf(b.y - m); b.z = __expf(b.z - m); b.w = __expf(b.w - m);
  float s = a.x + a.y + a.z + a.w + b.x + b.y + b.z + b.w;
#pragma unroll
  for (int o = 1; o < 64; o <<= 1) s += __shfl_xor(s, o);
  if ((tid & 63) == 0) sm[4 + (tid >> 6)] = s;
  __syncthreads();
  s = sm[4] + sm[5] + sm[6] + sm[7];
  float inv = 1.f / s;
  a.x *= inv; a.y *= inv; a.z *= inv; a.w *= inv;
  b.x *= inv; b.y *= inv; b.z *= inv; b.w *= inv;
  *(f4*)(b0 + tid * 8) = a;
  *(f4*)(b0 + tid * 8 + 4) = b;
}

// ---------------------------------------------------------------------------
// Partial rep over t-slices of 128: rp[n][sl][h*256+d]; probs at stride 4096.
// ---------------------------------------------------------------------------
__global__ void k_rep(const float* __restrict__ mv, const float* __restrict__ p,
                      float* __restrict__ rp) {
  __shared__ float pl[8][128];
  const int b = blockIdx.x;
  const int n = b >> 4, sl = b & 15;
  const int tid = threadIdx.x;
  for (int i = tid; i < 1024; i += 256) {
    int h = i >> 7, t = i & 127;
    pl[h][t] = p[(((size_t)h * 32 + n) << 12) + sl * 128 + t];
  }
  __syncthreads();
  float r[8] = {0.f, 0.f, 0.f, 0.f, 0.f, 0.f, 0.f, 0.f};
  const float* src = mv + (((size_t)n << 11) + sl * 128) * DD + tid;
#pragma unroll 4
  for (int tt = 0; tt < 128; ++tt) {
    float v = src[(size_t)tt * DD];
#pragma unroll
    for (int h = 0; h < 8; ++h) r[h] = fmaf(pl[h][tt], v, r[h]);
  }
  float* dst = rp + (((size_t)n * 16 + sl) << 11) + tid;
#pragma unroll
  for (int h = 0; h < 8; ++h) dst[h * 256] = r[h];
}

// ---------------------------------------------------------------------------
// out[n][i] = b[i] + sum_j concat[n][j] * Wo_w[i][j]
// ---------------------------------------------------------------------------
__global__ void k_out(const float* __restrict__ rp, const float* __restrict__ w,
                      const float* __restrict__ bias, float* __restrict__ out) {
  __shared__ float c[2048];
  const int n = blockIdx.x, tid = threadIdx.x;
  for (int j = tid; j < 2048; j += 256) {
    float s = 0.f;
#pragma unroll
    for (int sl = 0; sl < 16; ++sl) s += rp[(((size_t)n * 16 + sl) << 11) + j];
    c[j] = s;
  }
  __syncthreads();
  float acc = bias[tid];
  const f4* wrow = (const f4*)(w + (size_t)tid * 2048);
  const f4* cc = (const f4*)c;
  for (int j = 0; j < 512; ++j) {
    f4 wv = wrow[j];
    f4 cv = cc[j];
    acc += wv.x * cv.x + wv.y * cv.y + wv.z * cv.z + wv.w * cv.w;
  }
  out[n * 256 + tid] = acc;
}

extern "C" void kernel_launch(void* const* d_in, const int* in_sizes, int n_in,
                              void* d_out, int out_size, void* d_ws, size_t ws_size,
                              hipStream_t stream) {
  const float* ok  = (const float*)d_in[0];
  const float* mk  = (const float*)d_in[1];
  const float* mv  = (const float*)d_in[2];
  const float* wm  = (const float*)d_in[3];
  const float* wow = (const float*)d_in[4];
  const float* wob = (const float*)d_in[5];
  float* out = (float*)d_out;
  char* ws = (char*)d_ws;

  // ws: [0,4MB) sc2 partials/probs | [4,5MB) packB | [8,16MB) rep | [16,48MB) packA
  float* sc2 = (float*)ws;
  u16* pb    = (u16*)(ws + (4u << 20));
  float* rp  = (float*)(ws + (8u << 20));
  u16* pa    = (u16*)(ws + (16u << 20));

  hipLaunchKernelGGL(k_pack,    dim3(8448), dim3(256), 0, stream, mk, wm, pa, pb);
  hipLaunchKernelGGL(k_scoresf, dim3(8192), dim3(256), 0, stream, ok, pa, pb, sc2);
  hipLaunchKernelGGL(k_softmax, dim3(256),  dim3(256), 0, stream, sc2);
  hipLaunchKernelGGL(k_rep,     dim3(512),  dim3(256), 0, stream, mv, sc2, rp);
  hipLaunchKernelGGL(k_out,     dim3(32),   dim3(256), 0, stream, rp, wow, wob, out);
}